// Round 1
// baseline (479.510 us; speedup 1.0000x reference)
//
#include <hip/hip_runtime.h>
#include <math.h>

// Problem constants (B=2, N=2048, C=256, H=8, D=32)
#define Bb 2
#define Nn 2048
#define Cc 256
#define Hh 8
#define Dd 32
#define INNER 256           // H*D
#define TQKV 768            // 3*INNER
#define NROWS 4096          // B*N
#define EPSf 1e-5f
#define SCALEf 0.17677669529663687f  // 1/sqrt(32)

// workspace layout (float offsets)
#define OFF_NORMED 0u
#define OFF_QKV    1048576u   // [4096][768]
#define OFF_GATE   4194304u   // [4096][256]  sigmoid applied
#define OFF_M      5242880u   // [16][2048]   row max of scores
#define OFF_LINV   5275648u   // [16][2048]   1 / row sum of exp
#define OFF_AO     5308416u   // [4096][256]  gated attention out
// total 6,356,992 floats = 25.4 MB

// ---------------------------------------------------------------------------
// Kernel 1: LayerNorm (biased variance, matches torch/jax LN)
// ---------------------------------------------------------------------------
__global__ __launch_bounds__(256) void ln_kernel(
    const float* __restrict__ x, const float* __restrict__ gam,
    const float* __restrict__ bet, float* __restrict__ normed) {
  int row = blockIdx.x;
  int tid = threadIdx.x;
  size_t base = (size_t)row * Cc;
  float v = x[base + tid];
  float s1 = v, s2 = v * v;
  #pragma unroll
  for (int off = 32; off; off >>= 1) {
    s1 += __shfl_xor(s1, off);
    s2 += __shfl_xor(s2, off);
  }
  __shared__ float w1[4], w2[4];
  if ((tid & 63) == 0) { w1[tid >> 6] = s1; w2[tid >> 6] = s2; }
  __syncthreads();
  s1 = w1[0] + w1[1] + w1[2] + w1[3];
  s2 = w2[0] + w2[1] + w2[2] + w2[3];
  float mu = s1 * (1.0f / Cc);
  float var = s2 * (1.0f / Cc) - mu * mu;
  float rstd = rsqrtf(var + EPSf);
  normed[base + tid] = (v - mu) * rstd * gam[tid] + bet[tid];
}

// ---------------------------------------------------------------------------
// Kernel 2: fused projections. cols 0..767 = qkv (A=normed, W_qkv),
// cols 768..1023 = gate (A=x unnormalized, W_gate, +bias, sigmoid).
// Q columns (o<256) are pre-scaled by 1/sqrt(D).
// 64x64 tile per block, 256 threads, 4x4 micro-tile, K-chunks of 64.
// ---------------------------------------------------------------------------
__global__ __launch_bounds__(256) void proj_kernel(
    const float* __restrict__ x, const float* __restrict__ normed,
    const float* __restrict__ Wqkv, const float* __restrict__ Wgate,
    const float* __restrict__ bgate,
    float* __restrict__ qkv, float* __restrict__ gate) {
  int ro = blockIdx.y * 64;
  int co = blockIdx.x * 64;             // 0..1023
  bool isGate = (co >= TQKV);
  const float* __restrict__ A  = isGate ? x : normed;
  const float* __restrict__ Wm = isGate ? Wgate : Wqkv;
  int obase = isGate ? (co - TQKV) : co;
  int tid = threadIdx.x;
  int tx = tid & 15, ty = tid >> 4;
  __shared__ __align__(16) float a_lds[64][68];
  __shared__ __align__(16) float b_lds[64][68];
  float acc[4][4] = {};
  for (int k0 = 0; k0 < Cc; k0 += 64) {
    for (int i4 = tid; i4 < 1024; i4 += 256) {
      int rr = i4 >> 4, kq = (i4 & 15) << 2;
      *reinterpret_cast<float4*>(&a_lds[rr][kq]) =
          *reinterpret_cast<const float4*>(&A[(size_t)(ro + rr) * Cc + k0 + kq]);
      *reinterpret_cast<float4*>(&b_lds[rr][kq]) =
          *reinterpret_cast<const float4*>(&Wm[(size_t)(obase + rr) * Cc + k0 + kq]);
    }
    __syncthreads();
    #pragma unroll
    for (int kk = 0; kk < 64; kk += 4) {
      float4 av[4], bv[4];
      #pragma unroll
      for (int r = 0; r < 4; r++)
        av[r] = *reinterpret_cast<const float4*>(&a_lds[ty + 16 * r][kk]);
      #pragma unroll
      for (int c = 0; c < 4; c++)
        bv[c] = *reinterpret_cast<const float4*>(&b_lds[tx + 16 * c][kk]);
      #pragma unroll
      for (int r = 0; r < 4; r++)
        #pragma unroll
        for (int c = 0; c < 4; c++)
          acc[r][c] += av[r].x * bv[c].x + av[r].y * bv[c].y +
                       av[r].z * bv[c].z + av[r].w * bv[c].w;
    }
    __syncthreads();
  }
  #pragma unroll
  for (int r = 0; r < 4; r++) {
    int row = ro + ty + 16 * r;
    #pragma unroll
    for (int c = 0; c < 4; c++) {
      int o = obase + tx + 16 * c;
      float v = acc[r][c];
      if (isGate) {
        float z = v + bgate[o];
        gate[(size_t)row * INNER + o] = 1.0f / (1.0f + __expf(-z));
      } else {
        if (o < INNER) v *= SCALEf;   // fold attention scale into Q
        qkv[(size_t)row * TQKV + o] = v;
      }
    }
  }
}

// ---------------------------------------------------------------------------
// Kernel 3: per-row softmax stats. For each (b,h,i): m_i = max_j s_ij,
// linv_i = 1/sum_j exp(s_ij - m_i). Q is pre-scaled. 64 rows per block.
// ---------------------------------------------------------------------------
__global__ __launch_bounds__(256) void stats_kernel(
    const float* __restrict__ qkv, float* __restrict__ mrow,
    float* __restrict__ linv) {
  int bh = blockIdx.y;
  int b = bh >> 3, h = bh & 7;
  int i0 = blockIdx.x * 64;
  int tid = threadIdx.x;
  int tx = tid & 15, ty = tid >> 4;
  __shared__ __align__(16) float q_lds[64][36];
  __shared__ __align__(16) float k_lds[64][36];
  __shared__ float red_m[64][16];
  __shared__ float red_l[64][16];
  size_t qbase = ((size_t)(b * Nn + i0)) * TQKV + h * Dd;
  for (int i4 = tid; i4 < 512; i4 += 256) {
    int rr = i4 >> 3, dq = (i4 & 7) << 2;
    *reinterpret_cast<float4*>(&q_lds[rr][dq]) =
        *reinterpret_cast<const float4*>(&qkv[qbase + (size_t)rr * TQKV + dq]);
  }
  float mloc[4] = {-INFINITY, -INFINITY, -INFINITY, -INFINITY};
  float lloc[4] = {0.f, 0.f, 0.f, 0.f};
  for (int jt = 0; jt < 32; jt++) {
    size_t kbase = ((size_t)(b * Nn + jt * 64)) * TQKV + INNER + h * Dd;
    for (int i4 = tid; i4 < 512; i4 += 256) {
      int rr = i4 >> 3, dq = (i4 & 7) << 2;
      *reinterpret_cast<float4*>(&k_lds[rr][dq]) =
          *reinterpret_cast<const float4*>(&qkv[kbase + (size_t)rr * TQKV + dq]);
    }
    __syncthreads();
    float s[4][4] = {};
    #pragma unroll
    for (int d0 = 0; d0 < Dd; d0 += 4) {
      float4 qv[4], kv[4];
      #pragma unroll
      for (int r = 0; r < 4; r++)
        qv[r] = *reinterpret_cast<const float4*>(&q_lds[ty + 16 * r][d0]);
      #pragma unroll
      for (int c = 0; c < 4; c++)
        kv[c] = *reinterpret_cast<const float4*>(&k_lds[tx + 16 * c][d0]);
      #pragma unroll
      for (int r = 0; r < 4; r++)
        #pragma unroll
        for (int c = 0; c < 4; c++)
          s[r][c] += qv[r].x * kv[c].x + qv[r].y * kv[c].y +
                     qv[r].z * kv[c].z + qv[r].w * kv[c].w;
    }
    #pragma unroll
    for (int r = 0; r < 4; r++) {
      float mt = fmaxf(fmaxf(s[r][0], s[r][1]), fmaxf(s[r][2], s[r][3]));
      float mnew = fmaxf(mloc[r], mt);
      float lsum = __expf(s[r][0] - mnew) + __expf(s[r][1] - mnew) +
                   __expf(s[r][2] - mnew) + __expf(s[r][3] - mnew);
      lloc[r] = lloc[r] * __expf(mloc[r] - mnew) + lsum;
      mloc[r] = mnew;
    }
    __syncthreads();
  }
  #pragma unroll
  for (int r = 0; r < 4; r++) {
    red_m[ty + 16 * r][tx] = mloc[r];
    red_l[ty + 16 * r][tx] = lloc[r];
  }
  __syncthreads();
  if (tid < 64) {
    float M = -INFINITY;
    #pragma unroll
    for (int t = 0; t < 16; t++) M = fmaxf(M, red_m[tid][t]);
    float L = 0.f;
    #pragma unroll
    for (int t = 0; t < 16; t++) L += red_l[tid][t] * __expf(red_m[tid][t] - M);
    mrow[(size_t)bh * Nn + i0 + tid] = M;
    linv[(size_t)bh * Nn + i0 + tid] = 1.0f / L;
  }
}

// ---------------------------------------------------------------------------
// Kernel 4: out[j,d] = sum_i exp(s_ij - m_i) * (v[i,d]/l_i), times gate.
// Block owns one (b,h, 64-wide j-tile); loops over all 32 i-tiles.
// Phase A: S-tile (q rows = i, k rows = j) -> p_lds[j][i] (exp applied).
// Phase B: out[j][d] += p_lds[j][i] * v_lds[i][d]  (v pre-scaled by 1/l).
// ---------------------------------------------------------------------------
__global__ __launch_bounds__(256) void attnout_kernel(
    const float* __restrict__ qkv, const float* __restrict__ mrow,
    const float* __restrict__ linv, const float* __restrict__ gate,
    float* __restrict__ ao) {
  int bh = blockIdx.y;
  int b = bh >> 3, h = bh & 7;
  int j0 = blockIdx.x * 64;
  int tid = threadIdx.x;
  int tx = tid & 15, ty = tid >> 4;
  __shared__ __align__(16) float k_lds[64][36];
  __shared__ __align__(16) float q_lds[64][36];
  __shared__ __align__(16) float v_lds[64][36];
  __shared__ __align__(16) float p_lds[64][68];
  __shared__ float m_lds[64];
  size_t kbase = ((size_t)(b * Nn + j0)) * TQKV + INNER + h * Dd;
  for (int i4 = tid; i4 < 512; i4 += 256) {
    int rr = i4 >> 3, dq = (i4 & 7) << 2;
    *reinterpret_cast<float4*>(&k_lds[rr][dq]) =
        *reinterpret_cast<const float4*>(&qkv[kbase + (size_t)rr * TQKV + dq]);
  }
  float acc[4][2] = {};
  for (int it = 0; it < 32; it++) {
    int i0 = it * 64;
    size_t qb = ((size_t)(b * Nn + i0)) * TQKV + h * Dd;
    size_t vb = qb + 2 * INNER;
    __syncthreads();  // protects p/q/v_lds from previous iteration's readers
    for (int i4 = tid; i4 < 512; i4 += 256) {
      int rr = i4 >> 3, dq = (i4 & 7) << 2;
      *reinterpret_cast<float4*>(&q_lds[rr][dq]) =
          *reinterpret_cast<const float4*>(&qkv[qb + (size_t)rr * TQKV + dq]);
      float4 vv = *reinterpret_cast<const float4*>(&qkv[vb + (size_t)rr * TQKV + dq]);
      float rl = linv[(size_t)bh * Nn + i0 + rr];
      vv.x *= rl; vv.y *= rl; vv.z *= rl; vv.w *= rl;
      *reinterpret_cast<float4*>(&v_lds[rr][dq]) = vv;
    }
    if (tid < 64) m_lds[tid] = mrow[(size_t)bh * Nn + i0 + tid];
    __syncthreads();
    // Phase A: s[i][j], i = ty+16r (q rows), j = tx+16c (k rows)
    float s[4][4] = {};
    #pragma unroll
    for (int d0 = 0; d0 < Dd; d0 += 4) {
      float4 qv[4], kv[4];
      #pragma unroll
      for (int r = 0; r < 4; r++)
        qv[r] = *reinterpret_cast<const float4*>(&q_lds[ty + 16 * r][d0]);
      #pragma unroll
      for (int c = 0; c < 4; c++)
        kv[c] = *reinterpret_cast<const float4*>(&k_lds[tx + 16 * c][d0]);
      #pragma unroll
      for (int r = 0; r < 4; r++)
        #pragma unroll
        for (int c = 0; c < 4; c++)
          s[r][c] += qv[r].x * kv[c].x + qv[r].y * kv[c].y +
                     qv[r].z * kv[c].z + qv[r].w * kv[c].w;
    }
    #pragma unroll
    for (int r = 0; r < 4; r++) {
      float mi = m_lds[ty + 16 * r];
      #pragma unroll
      for (int c = 0; c < 4; c++)
        p_lds[tx + 16 * c][ty + 16 * r] = __expf(s[r][c] - mi);
    }
    __syncthreads();
    // Phase B: j = ty+16r, d = 2*tx + {0,1}
    #pragma unroll
    for (int ib = 0; ib < 16; ib++) {
      float4 pv[4];
      #pragma unroll
      for (int r = 0; r < 4; r++)
        pv[r] = *reinterpret_cast<const float4*>(&p_lds[ty + 16 * r][ib * 4]);
      float2 vv[4];
      #pragma unroll
      for (int ii = 0; ii < 4; ii++)
        vv[ii] = *reinterpret_cast<const float2*>(&v_lds[ib * 4 + ii][2 * tx]);
      #pragma unroll
      for (int r = 0; r < 4; r++) {
        acc[r][0] += pv[r].x * vv[0].x + pv[r].y * vv[1].x +
                     pv[r].z * vv[2].x + pv[r].w * vv[3].x;
        acc[r][1] += pv[r].x * vv[0].y + pv[r].y * vv[1].y +
                     pv[r].z * vv[2].y + pv[r].w * vv[3].y;
      }
    }
  }
  #pragma unroll
  for (int r = 0; r < 4; r++) {
    int j = j0 + ty + 16 * r;
    size_t idx = ((size_t)(b * Nn + j)) * INNER + h * Dd + 2 * tx;
    float2 g2 = *reinterpret_cast<const float2*>(&gate[idx]);
    float2 o2;
    o2.x = acc[r][0] * g2.x;
    o2.y = acc[r][1] * g2.y;
    *reinterpret_cast<float2*>(&ao[idx]) = o2;
  }
}

// ---------------------------------------------------------------------------
// Kernel 5: y = x + ao @ W_final^T + b_final
// ---------------------------------------------------------------------------
__global__ __launch_bounds__(256) void final_kernel(
    const float* __restrict__ ao, const float* __restrict__ Wf,
    const float* __restrict__ bf, const float* __restrict__ x,
    float* __restrict__ out) {
  int ro = blockIdx.y * 64;
  int co = blockIdx.x * 64;   // 0..255
  int tid = threadIdx.x;
  int tx = tid & 15, ty = tid >> 4;
  __shared__ __align__(16) float a_lds[64][68];
  __shared__ __align__(16) float b_lds[64][68];
  float acc[4][4] = {};
  for (int k0 = 0; k0 < INNER; k0 += 64) {
    for (int i4 = tid; i4 < 1024; i4 += 256) {
      int rr = i4 >> 4, kq = (i4 & 15) << 2;
      *reinterpret_cast<float4*>(&a_lds[rr][kq]) =
          *reinterpret_cast<const float4*>(&ao[(size_t)(ro + rr) * INNER + k0 + kq]);
      *reinterpret_cast<float4*>(&b_lds[rr][kq]) =
          *reinterpret_cast<const float4*>(&Wf[(size_t)(co + rr) * INNER + k0 + kq]);
    }
    __syncthreads();
    #pragma unroll
    for (int kk = 0; kk < 64; kk += 4) {
      float4 av[4], bv[4];
      #pragma unroll
      for (int r = 0; r < 4; r++)
        av[r] = *reinterpret_cast<const float4*>(&a_lds[ty + 16 * r][kk]);
      #pragma unroll
      for (int c = 0; c < 4; c++)
        bv[c] = *reinterpret_cast<const float4*>(&b_lds[tx + 16 * c][kk]);
      #pragma unroll
      for (int r = 0; r < 4; r++)
        #pragma unroll
        for (int c = 0; c < 4; c++)
          acc[r][c] += av[r].x * bv[c].x + av[r].y * bv[c].y +
                       av[r].z * bv[c].z + av[r].w * bv[c].w;
    }
    __syncthreads();
  }
  #pragma unroll
  for (int r = 0; r < 4; r++) {
    int row = ro + ty + 16 * r;
    #pragma unroll
    for (int c = 0; c < 4; c++) {
      int o = co + tx + 16 * c;
      out[(size_t)row * Cc + o] = x[(size_t)row * Cc + o] + acc[r][c] + bf[o];
    }
  }
}

// ---------------------------------------------------------------------------
extern "C" void kernel_launch(void* const* d_in, const int* in_sizes, int n_in,
                              void* d_out, int out_size, void* d_ws, size_t ws_size,
                              hipStream_t stream) {
  (void)in_sizes; (void)n_in; (void)out_size; (void)ws_size;
  const float* x     = (const float*)d_in[0];
  const float* gam   = (const float*)d_in[1];
  const float* bet   = (const float*)d_in[2];
  const float* Wqkv  = (const float*)d_in[3];
  const float* Wgate = (const float*)d_in[4];
  const float* bgate = (const float*)d_in[5];
  const float* Wf    = (const float*)d_in[6];
  const float* bf    = (const float*)d_in[7];
  float* out = (float*)d_out;
  float* ws  = (float*)d_ws;

  float* normed = ws + OFF_NORMED;
  float* qkv    = ws + OFF_QKV;
  float* gate   = ws + OFF_GATE;
  float* mr     = ws + OFF_M;
  float* li     = ws + OFF_LINV;
  float* ao     = ws + OFF_AO;

  ln_kernel<<<NROWS, 256, 0, stream>>>(x, gam, bet, normed);
  proj_kernel<<<dim3(16, 64), 256, 0, stream>>>(x, normed, Wqkv, Wgate, bgate, qkv, gate);
  stats_kernel<<<dim3(32, 16), 256, 0, stream>>>(qkv, mr, li);
  attnout_kernel<<<dim3(32, 16), 256, 0, stream>>>(qkv, mr, li, gate, ao);
  final_kernel<<<dim3(4, 64), 256, 0, stream>>>(ao, Wf, bf, x, out);
}

// Round 2
// 285.460 us; speedup vs baseline: 1.6798x; 1.6798x over previous
//
#include <hip/hip_runtime.h>
#include <math.h>

// Problem constants (B=2, N=2048, C=256, H=8, D=32)
#define Bb 2
#define Nn 2048
#define Cc 256
#define Hh 8
#define Dd 32
#define INNER 256           // H*D
#define TQKV 768            // 3*INNER
#define NROWS 4096          // B*N
#define EPSf 1e-5f
#define SCALEf 0.17677669529663687f  // 1/sqrt(32)

typedef unsigned short u16;
typedef short s16x8 __attribute__((ext_vector_type(8)));
typedef float f32x4 __attribute__((ext_vector_type(4)));
#define MFMA16 __builtin_amdgcn_mfma_f32_16x16x32_bf16

// workspace layout (float offsets); total 6,324,224 floats = 25.3 MB
#define OFF_NORMED 0u          // [4096][256] f32
#define OFF_GATE   1048576u    // [4096][256] f32 (sigmoid applied)
#define OFF_AO     2097152u    // [4096][256] f32
#define OFF_MM     3145728u    // [16][2048] f32:  m_i + log(l_i)
#define OFF_QHI    3178496u    // [4096][768] bf16 (as u16)
#define OFF_QLO    4751360u    // [4096][768] bf16 (as u16)

// bf16 helpers (RNE)
__device__ inline u16 f2bf(float f) {
  union { float f; unsigned u; } v; v.f = f;
  unsigned r = v.u + 0x7fffu + ((v.u >> 16) & 1u);
  return (u16)(r >> 16);
}
__device__ inline float bf2f(u16 h) {
  union { unsigned u; float f; } v; v.u = ((unsigned)h) << 16;
  return v.f;
}

// ---------------------------------------------------------------------------
// Kernel 1: LayerNorm (biased variance)
// ---------------------------------------------------------------------------
__global__ __launch_bounds__(256) void ln_kernel(
    const float* __restrict__ x, const float* __restrict__ gam,
    const float* __restrict__ bet, float* __restrict__ normed) {
  int row = blockIdx.x;
  int tid = threadIdx.x;
  size_t base = (size_t)row * Cc;
  float v = x[base + tid];
  float s1 = v, s2 = v * v;
  #pragma unroll
  for (int off = 32; off; off >>= 1) {
    s1 += __shfl_xor(s1, off);
    s2 += __shfl_xor(s2, off);
  }
  __shared__ float w1[4], w2[4];
  if ((tid & 63) == 0) { w1[tid >> 6] = s1; w2[tid >> 6] = s2; }
  __syncthreads();
  s1 = w1[0] + w1[1] + w1[2] + w1[3];
  s2 = w2[0] + w2[1] + w2[2] + w2[3];
  float mu = s1 * (1.0f / Cc);
  float var = s2 * (1.0f / Cc) - mu * mu;
  float rstd = rsqrtf(var + EPSf);
  normed[base + tid] = (v - mu) * rstd * gam[tid] + bet[tid];
}

// ---------------------------------------------------------------------------
// Kernel 2: fused projections (fp32 compute). qkv outputs are written as
// split bf16 (hi + lo) for the MFMA attention kernels; gate stays fp32.
// Q columns (o<256) pre-scaled by 1/sqrt(D).
// ---------------------------------------------------------------------------
__global__ __launch_bounds__(256) void proj_kernel(
    const float* __restrict__ x, const float* __restrict__ normed,
    const float* __restrict__ Wqkv, const float* __restrict__ Wgate,
    const float* __restrict__ bgate,
    u16* __restrict__ qhi, u16* __restrict__ qlo, float* __restrict__ gate) {
  int ro = blockIdx.y * 64;
  int co = blockIdx.x * 64;             // 0..1023
  bool isGate = (co >= TQKV);
  const float* __restrict__ A  = isGate ? x : normed;
  const float* __restrict__ Wm = isGate ? Wgate : Wqkv;
  int obase = isGate ? (co - TQKV) : co;
  int tid = threadIdx.x;
  int tx = tid & 15, ty = tid >> 4;
  __shared__ __align__(16) float a_lds[64][68];
  __shared__ __align__(16) float b_lds[64][68];
  float acc[4][4] = {};
  for (int k0 = 0; k0 < Cc; k0 += 64) {
    for (int i4 = tid; i4 < 1024; i4 += 256) {
      int rr = i4 >> 4, kq = (i4 & 15) << 2;
      *reinterpret_cast<float4*>(&a_lds[rr][kq]) =
          *reinterpret_cast<const float4*>(&A[(size_t)(ro + rr) * Cc + k0 + kq]);
      *reinterpret_cast<float4*>(&b_lds[rr][kq]) =
          *reinterpret_cast<const float4*>(&Wm[(size_t)(obase + rr) * Cc + k0 + kq]);
    }
    __syncthreads();
    #pragma unroll
    for (int kk = 0; kk < 64; kk += 4) {
      float4 av[4], bv[4];
      #pragma unroll
      for (int r = 0; r < 4; r++)
        av[r] = *reinterpret_cast<const float4*>(&a_lds[ty + 16 * r][kk]);
      #pragma unroll
      for (int c = 0; c < 4; c++)
        bv[c] = *reinterpret_cast<const float4*>(&b_lds[tx + 16 * c][kk]);
      #pragma unroll
      for (int r = 0; r < 4; r++)
        #pragma unroll
        for (int c = 0; c < 4; c++)
          acc[r][c] += av[r].x * bv[c].x + av[r].y * bv[c].y +
                       av[r].z * bv[c].z + av[r].w * bv[c].w;
    }
    __syncthreads();
  }
  #pragma unroll
  for (int r = 0; r < 4; r++) {
    int row = ro + ty + 16 * r;
    #pragma unroll
    for (int c = 0; c < 4; c++) {
      int o = obase + tx + 16 * c;
      float v = acc[r][c];
      if (isGate) {
        float z = v + bgate[o];
        gate[(size_t)row * INNER + o] = 1.0f / (1.0f + __expf(-z));
      } else {
        if (o < INNER) v *= SCALEf;   // fold attention scale into Q
        u16 hb = f2bf(v);
        qhi[(size_t)row * TQKV + o] = hb;
        qlo[(size_t)row * TQKV + o] = f2bf(v - bf2f(hb));
      }
    }
  }
}

// ---------------------------------------------------------------------------
// Kernel 3: softmax stats via split-bf16 MFMA.
// Per (b,h, 64-wide i-strip): mm_i = m_i + log(sum_j exp(s_ij - m_i)).
// mfma(A=K-rows(j), B=Q-rows(i)) -> D[m=j][n=i]. Per-lane online stats over
// its j-subset, combined across lanes (shfl) and waves (LDS).
// ---------------------------------------------------------------------------
__global__ __launch_bounds__(256) void stats_kernel(
    const u16* __restrict__ qhi, const u16* __restrict__ qlo,
    float* __restrict__ mmrow) {
  int bh = blockIdx.y;
  int b = bh >> 3, h = bh & 7;
  int i0 = blockIdx.x * 64;
  int tid = threadIdx.x;
  int w = tid >> 6;
  int l = tid & 63;
  int l15 = l & 15, g = l >> 4;
  __shared__ u16 q_hi[64][40], q_lo[64][40];
  __shared__ u16 k_hi[64][40], k_lo[64][40];
  __shared__ float red_m[4][64], red_l[4][64];

  int srow = tid >> 2, sc = tid & 3;
  {
    size_t gq = ((size_t)(b * Nn + i0 + srow)) * TQKV + h * Dd + 8 * sc;
    *reinterpret_cast<uint4*>(&q_hi[srow][8 * sc]) =
        *reinterpret_cast<const uint4*>(&qhi[gq]);
    *reinterpret_cast<uint4*>(&q_lo[srow][8 * sc]) =
        *reinterpret_cast<const uint4*>(&qlo[gq]);
  }
  __syncthreads();
  s16x8 bq_hi[4], bq_lo[4];
  #pragma unroll
  for (int nt = 0; nt < 4; nt++) {
    bq_hi[nt] = *reinterpret_cast<const s16x8*>(&q_hi[l15 + 16 * nt][8 * g]);
    bq_lo[nt] = *reinterpret_cast<const s16x8*>(&q_lo[l15 + 16 * nt][8 * g]);
  }
  float m[4], lsum[4];
  #pragma unroll
  for (int nt = 0; nt < 4; nt++) { m[nt] = -INFINITY; lsum[nt] = 0.f; }

  for (int jt = 0; jt < 32; jt++) {
    __syncthreads();
    size_t gk = ((size_t)(b * Nn + jt * 64 + srow)) * TQKV + INNER + h * Dd + 8 * sc;
    *reinterpret_cast<uint4*>(&k_hi[srow][8 * sc]) =
        *reinterpret_cast<const uint4*>(&qhi[gk]);
    *reinterpret_cast<uint4*>(&k_lo[srow][8 * sc]) =
        *reinterpret_cast<const uint4*>(&qlo[gk]);
    __syncthreads();
    s16x8 ka_hi = *reinterpret_cast<const s16x8*>(&k_hi[l15 + 16 * w][8 * g]);
    s16x8 ka_lo = *reinterpret_cast<const s16x8*>(&k_lo[l15 + 16 * w][8 * g]);
    #pragma unroll
    for (int nt = 0; nt < 4; nt++) {
      f32x4 acc = {0.f, 0.f, 0.f, 0.f};
      acc = MFMA16(ka_hi, bq_hi[nt], acc, 0, 0, 0);
      acc = MFMA16(ka_hi, bq_lo[nt], acc, 0, 0, 0);
      acc = MFMA16(ka_lo, bq_hi[nt], acc, 0, 0, 0);
      float mt = fmaxf(fmaxf(acc[0], acc[1]), fmaxf(acc[2], acc[3]));
      float mn = fmaxf(m[nt], mt);
      float ls = __expf(acc[0] - mn) + __expf(acc[1] - mn) +
                 __expf(acc[2] - mn) + __expf(acc[3] - mn);
      lsum[nt] = lsum[nt] * __expf(m[nt] - mn) + ls;
      m[nt] = mn;
    }
  }
  #pragma unroll
  for (int off = 16; off <= 32; off <<= 1) {
    #pragma unroll
    for (int nt = 0; nt < 4; nt++) {
      float mo = __shfl_xor(m[nt], off);
      float lo = __shfl_xor(lsum[nt], off);
      float mn = fmaxf(m[nt], mo);
      lsum[nt] = lsum[nt] * __expf(m[nt] - mn) + lo * __expf(mo - mn);
      m[nt] = mn;
    }
  }
  if (g == 0) {
    #pragma unroll
    for (int nt = 0; nt < 4; nt++) {
      red_m[w][l15 + 16 * nt] = m[nt];
      red_l[w][l15 + 16 * nt] = lsum[nt];
    }
  }
  __syncthreads();
  if (tid < 64) {
    float M = fmaxf(fmaxf(red_m[0][tid], red_m[1][tid]),
                    fmaxf(red_m[2][tid], red_m[3][tid]));
    float L = red_l[0][tid] * __expf(red_m[0][tid] - M)
            + red_l[1][tid] * __expf(red_m[1][tid] - M)
            + red_l[2][tid] * __expf(red_m[2][tid] - M)
            + red_l[3][tid] * __expf(red_m[3][tid] - M);
    mmrow[(size_t)bh * Nn + i0 + tid] = M + __logf(L);
  }
}

// ---------------------------------------------------------------------------
// Kernel 4: out[j,d] = sum_i exp(s_ij - mm_i) * v[i,d], times gate.
// Block owns (b,h, 64-wide j-tile); loops i-tiles. Wave w owns j-strip
// [16w,16w+16) through QK (as B n-tile), P storage, PV (as A m-tile), output.
// P round-trips through LDS as split bf16. V^T staged with XOR swizzle
// (bits>=3 only, so 8-elem MFMA k-fragments are not internally permuted).
// ---------------------------------------------------------------------------
__global__ __launch_bounds__(256) void attnout_kernel(
    const u16* __restrict__ qhi, const u16* __restrict__ qlo,
    const float* __restrict__ mmrow, const float* __restrict__ gate,
    float* __restrict__ ao) {
  int bh = blockIdx.y;
  int b = bh >> 3, h = bh & 7;
  int j0 = blockIdx.x * 64;
  int tid = threadIdx.x;
  int w = tid >> 6;
  int l = tid & 63;
  int l15 = l & 15, g = l >> 4;
  __shared__ u16 k_hi[64][40], k_lo[64][40];
  __shared__ u16 q_hi[64][40], q_lo[64][40];
  __shared__ u16 vt_hi[32][72], vt_lo[32][72];
  __shared__ u16 p_hi[64][72], p_lo[64][72];
  __shared__ float mm_lds[64];

  int srow = tid >> 2, sc = tid & 3;
  {
    size_t gk = ((size_t)(b * Nn + j0 + srow)) * TQKV + INNER + h * Dd + 8 * sc;
    *reinterpret_cast<uint4*>(&k_hi[srow][8 * sc]) =
        *reinterpret_cast<const uint4*>(&qhi[gk]);
    *reinterpret_cast<uint4*>(&k_lo[srow][8 * sc]) =
        *reinterpret_cast<const uint4*>(&qlo[gk]);
  }
  __syncthreads();
  s16x8 kb_hi = *reinterpret_cast<const s16x8*>(&k_hi[l15 + 16 * w][8 * g]);
  s16x8 kb_lo = *reinterpret_cast<const s16x8*>(&k_lo[l15 + 16 * w][8 * g]);

  f32x4 accd0 = {0.f, 0.f, 0.f, 0.f};
  f32x4 accd1 = {0.f, 0.f, 0.f, 0.f};
  int xorv = 8 * (l15 >> 2);

  for (int it = 0; it < 32; it++) {
    int i0 = it * 64;
    __syncthreads();   // prev iter's LDS reads complete
    // stage Q rows i
    size_t gq = ((size_t)(b * Nn + i0 + srow)) * TQKV + h * Dd + 8 * sc;
    *reinterpret_cast<uint4*>(&q_hi[srow][8 * sc]) =
        *reinterpret_cast<const uint4*>(&qhi[gq]);
    *reinterpret_cast<uint4*>(&q_lo[srow][8 * sc]) =
        *reinterpret_cast<const uint4*>(&qlo[gq]);
    // stage V^T (transpose with column XOR swizzle)
    size_t gv = gq + 2 * INNER;
    uint4 vh4 = *reinterpret_cast<const uint4*>(&qhi[gv]);
    uint4 vl4 = *reinterpret_cast<const uint4*>(&qlo[gv]);
    const u16* vhp = reinterpret_cast<const u16*>(&vh4);
    const u16* vlp = reinterpret_cast<const u16*>(&vl4);
    #pragma unroll
    for (int e = 0; e < 8; e++) {
      int d = 8 * sc + e;
      int col = srow ^ (8 * ((d >> 2) & 3));
      vt_hi[d][col] = vhp[e];
      vt_lo[d][col] = vlp[e];
    }
    if (tid < 64) mm_lds[tid] = mmrow[(size_t)bh * Nn + i0 + tid];
    __syncthreads();
    // QK^T + exp + split + store P[j][i]
    #pragma unroll
    for (int mt = 0; mt < 4; mt++) {
      s16x8 qa_hi = *reinterpret_cast<const s16x8*>(&q_hi[l15 + 16 * mt][8 * g]);
      s16x8 qa_lo = *reinterpret_cast<const s16x8*>(&q_lo[l15 + 16 * mt][8 * g]);
      f32x4 s = {0.f, 0.f, 0.f, 0.f};
      s = MFMA16(qa_hi, kb_hi, s, 0, 0, 0);
      s = MFMA16(qa_hi, kb_lo, s, 0, 0, 0);
      s = MFMA16(qa_lo, kb_hi, s, 0, 0, 0);
      int ib = 16 * mt + 4 * g;   // i base; D row m = 4g+r
      u16 ph[4], pl[4];
      #pragma unroll
      for (int r = 0; r < 4; r++) {
        float p = __expf(s[r] - mm_lds[ib + r]);
        u16 hb = f2bf(p);
        ph[r] = hb;
        pl[r] = f2bf(p - bf2f(hb));
      }
      ushort4 t1 = make_ushort4(ph[0], ph[1], ph[2], ph[3]);
      *reinterpret_cast<ushort4*>(&p_hi[l15 + 16 * w][ib]) = t1;
      ushort4 t2 = make_ushort4(pl[0], pl[1], pl[2], pl[3]);
      *reinterpret_cast<ushort4*>(&p_lo[l15 + 16 * w][ib]) = t2;
    }
    __syncthreads();
    // PV: D[m=j][n=d] += sum_i P^T[j,i] V[i,d]
    #pragma unroll
    for (int ks = 0; ks < 2; ks++) {
      s16x8 pa_hi = *reinterpret_cast<const s16x8*>(&p_hi[l15 + 16 * w][8 * g + 32 * ks]);
      s16x8 pa_lo = *reinterpret_cast<const s16x8*>(&p_lo[l15 + 16 * w][8 * g + 32 * ks]);
      int col = (8 * g + 32 * ks) ^ xorv;
      {
        s16x8 vb_hi = *reinterpret_cast<const s16x8*>(&vt_hi[l15][col]);
        s16x8 vb_lo = *reinterpret_cast<const s16x8*>(&vt_lo[l15][col]);
        accd0 = MFMA16(pa_hi, vb_hi, accd0, 0, 0, 0);
        accd0 = MFMA16(pa_hi, vb_lo, accd0, 0, 0, 0);
        accd0 = MFMA16(pa_lo, vb_hi, accd0, 0, 0, 0);
      }
      {
        s16x8 vb_hi = *reinterpret_cast<const s16x8*>(&vt_hi[l15 + 16][col]);
        s16x8 vb_lo = *reinterpret_cast<const s16x8*>(&vt_lo[l15 + 16][col]);
        accd1 = MFMA16(pa_hi, vb_hi, accd1, 0, 0, 0);
        accd1 = MFMA16(pa_hi, vb_lo, accd1, 0, 0, 0);
        accd1 = MFMA16(pa_lo, vb_hi, accd1, 0, 0, 0);
      }
    }
  }
  // epilogue: j = j0 + 16w + 4g + r, d = l15 + 16nt
  #pragma unroll
  for (int r = 0; r < 4; r++) {
    int j = j0 + 16 * w + 4 * g + r;
    size_t rowb = ((size_t)(b * Nn + j)) * INNER + h * Dd;
    size_t i0x = rowb + l15;
    ao[i0x] = accd0[r] * gate[i0x];
    size_t i1x = rowb + l15 + 16;
    ao[i1x] = accd1[r] * gate[i1x];
  }
}

// ---------------------------------------------------------------------------
// Kernel 5: y = x + ao @ W_final^T + b_final  (fp32)
// ---------------------------------------------------------------------------
__global__ __launch_bounds__(256) void final_kernel(
    const float* __restrict__ ao, const float* __restrict__ Wf,
    const float* __restrict__ bf, const float* __restrict__ x,
    float* __restrict__ out) {
  int ro = blockIdx.y * 64;
  int co = blockIdx.x * 64;   // 0..255
  int tid = threadIdx.x;
  int tx = tid & 15, ty = tid >> 4;
  __shared__ __align__(16) float a_lds[64][68];
  __shared__ __align__(16) float b_lds[64][68];
  float acc[4][4] = {};
  for (int k0 = 0; k0 < INNER; k0 += 64) {
    for (int i4 = tid; i4 < 1024; i4 += 256) {
      int rr = i4 >> 4, kq = (i4 & 15) << 2;
      *reinterpret_cast<float4*>(&a_lds[rr][kq]) =
          *reinterpret_cast<const float4*>(&ao[(size_t)(ro + rr) * INNER + k0 + kq]);
      *reinterpret_cast<float4*>(&b_lds[rr][kq]) =
          *reinterpret_cast<const float4*>(&Wf[(size_t)(co + rr) * INNER + k0 + kq]);
    }
    __syncthreads();
    #pragma unroll
    for (int kk = 0; kk < 64; kk += 4) {
      float4 av[4], bv[4];
      #pragma unroll
      for (int r = 0; r < 4; r++)
        av[r] = *reinterpret_cast<const float4*>(&a_lds[ty + 16 * r][kk]);
      #pragma unroll
      for (int c = 0; c < 4; c++)
        bv[c] = *reinterpret_cast<const float4*>(&b_lds[tx + 16 * c][kk]);
      #pragma unroll
      for (int r = 0; r < 4; r++)
        #pragma unroll
        for (int c = 0; c < 4; c++)
          acc[r][c] += av[r].x * bv[c].x + av[r].y * bv[c].y +
                       av[r].z * bv[c].z + av[r].w * bv[c].w;
    }
    __syncthreads();
  }
  #pragma unroll
  for (int r = 0; r < 4; r++) {
    int row = ro + ty + 16 * r;
    #pragma unroll
    for (int c = 0; c < 4; c++) {
      int o = co + tx + 16 * c;
      out[(size_t)row * Cc + o] = x[(size_t)row * Cc + o] + acc[r][c] + bf[o];
    }
  }
}

// ---------------------------------------------------------------------------
extern "C" void kernel_launch(void* const* d_in, const int* in_sizes, int n_in,
                              void* d_out, int out_size, void* d_ws, size_t ws_size,
                              hipStream_t stream) {
  (void)in_sizes; (void)n_in; (void)out_size; (void)ws_size;
  const float* x     = (const float*)d_in[0];
  const float* gam   = (const float*)d_in[1];
  const float* bet   = (const float*)d_in[2];
  const float* Wqkv  = (const float*)d_in[3];
  const float* Wgate = (const float*)d_in[4];
  const float* bgate = (const float*)d_in[5];
  const float* Wf    = (const float*)d_in[6];
  const float* bf    = (const float*)d_in[7];
  float* out = (float*)d_out;
  float* ws  = (float*)d_ws;

  float* normed = ws + OFF_NORMED;
  float* gatep  = ws + OFF_GATE;
  float* ao     = ws + OFF_AO;
  float* mm     = ws + OFF_MM;
  u16*   qhi    = (u16*)(ws + OFF_QHI);
  u16*   qlo    = (u16*)(ws + OFF_QLO);

  ln_kernel<<<NROWS, 256, 0, stream>>>(x, gam, bet, normed);
  proj_kernel<<<dim3(16, 64), 256, 0, stream>>>(x, normed, Wqkv, Wgate, bgate,
                                                qhi, qlo, gatep);
  stats_kernel<<<dim3(32, 16), 256, 0, stream>>>(qhi, qlo, mm);
  attnout_kernel<<<dim3(32, 16), 256, 0, stream>>>(qhi, qlo, mm, gatep, ao);
  final_kernel<<<dim3(4, 64), 256, 0, stream>>>(ao, Wf, bf, x, out);
}

// Round 5
// 199.213 us; speedup vs baseline: 2.4070x; 1.4329x over previous
//
#include <hip/hip_runtime.h>
#include <math.h>

// Problem constants (B=2, N=2048, C=256, H=8, D=32)
#define Bb 2
#define Nn 2048
#define Cc 256
#define Hh 8
#define Dd 32
#define INNER 256           // H*D
#define TQKV 768            // 3*INNER
#define NROWS 4096          // B*N
#define EPSf 1e-5f
#define SCALEf 0.17677669529663687f  // 1/sqrt(32)

typedef unsigned short u16;
typedef short s16x8 __attribute__((ext_vector_type(8)));
typedef float f32x4 __attribute__((ext_vector_type(4)));
#define MFMA16 __builtin_amdgcn_mfma_f32_16x16x32_bf16

// workspace layout (float offsets); total 5,603,328 floats = 22.4 MB
#define OFF_NORMED 0u          // [4096][256] f32   (dead after proj)
#define OFF_AOHI   0u          // [4096][256] u16   (aliases normed)
#define OFF_AOLO   524288u     // [4096][256] u16   (aliases normed)
#define OFF_GATE   1048576u    // [4096][256] f32 (sigmoid applied)
#define OFF_MM     2097152u    // [16][2048] f32:  m_i + log(l_i)
#define OFF_QHI    2129920u    // [4096][768] bf16 (as u16)
#define OFF_QLO    3702784u    // [4096][768] bf16 (as u16)
#define OFF_WHI    5275648u    // [1280][256] u16: Wqkv(Q-scaled) | Wgate | Wf
#define OFF_WLO    5439488u    // [1280][256] u16

// bf16 helpers (RNE)
__device__ inline u16 f2bf(float f) {
  union { float f; unsigned u; } v; v.f = f;
  unsigned r = v.u + 0x7fffu + ((v.u >> 16) & 1u);
  return (u16)(r >> 16);
}
__device__ inline float bf2f(u16 h) {
  union { unsigned u; float f; } v; v.u = ((unsigned)h) << 16;
  return v.f;
}

// ---------------------------------------------------------------------------
// Kernel 1: LayerNorm (biased variance)
// ---------------------------------------------------------------------------
__global__ __launch_bounds__(256) void ln_kernel(
    const float* __restrict__ x, const float* __restrict__ gam,
    const float* __restrict__ bet, float* __restrict__ normed) {
  int row = blockIdx.x;
  int tid = threadIdx.x;
  size_t base = (size_t)row * Cc;
  float v = x[base + tid];
  float s1 = v, s2 = v * v;
  #pragma unroll
  for (int off = 32; off; off >>= 1) {
    s1 += __shfl_xor(s1, off);
    s2 += __shfl_xor(s2, off);
  }
  __shared__ float w1[4], w2[4];
  if ((tid & 63) == 0) { w1[tid >> 6] = s1; w2[tid >> 6] = s2; }
  __syncthreads();
  s1 = w1[0] + w1[1] + w1[2] + w1[3];
  s2 = w2[0] + w2[1] + w2[2] + w2[3];
  float mu = s1 * (1.0f / Cc);
  float var = s2 * (1.0f / Cc) - mu * mu;
  float rstd = rsqrtf(var + EPSf);
  normed[base + tid] = (v - mu) * rstd * gam[tid] + bet[tid];
}

// ---------------------------------------------------------------------------
// Kernel 1b: weight split-bf16 conversion.
// Combined rows: [0,768) Wqkv (rows<256 scaled by 1/sqrt(D)), [768,1024)
// Wgate, [1024,1280) Wf.
// ---------------------------------------------------------------------------
__global__ __launch_bounds__(256) void wconv_kernel(
    const float* __restrict__ Wqkv, const float* __restrict__ Wgate,
    const float* __restrict__ Wf, u16* __restrict__ whi, u16* __restrict__ wlo) {
  int row = blockIdx.x;
  int col = threadIdx.x;
  float v;
  if (row < TQKV) {
    v = Wqkv[(size_t)row * Cc + col];
    if (row < INNER) v *= SCALEf;   // fold attention scale into Q weights
  } else if (row < TQKV + INNER) {
    v = Wgate[(size_t)(row - TQKV) * Cc + col];
  } else {
    v = Wf[(size_t)(row - TQKV - INNER) * Cc + col];
  }
  u16 h = f2bf(v);
  whi[(size_t)row * Cc + col] = h;
  wlo[(size_t)row * Cc + col] = f2bf(v - bf2f(h));
}

// ---------------------------------------------------------------------------
// Kernel 2: fused projections via split-bf16 MFMA.
// C[4096 x 1024] = A @ W^T; cols 0..767 qkv (A=normed, out split-bf16),
// cols 768..1023 gate (A=x, +bias, sigmoid, out fp32).
// 64x64 tile, K-chunks of 64. A staged fp32->hi/lo at LDS-write time.
// Wave w owns 16-col strip; 4 m-tiles of 16 rows; D[m][n]: m=A-row, n=W-row.
// ---------------------------------------------------------------------------
__global__ __launch_bounds__(256) void proj_kernel(
    const float* __restrict__ x, const float* __restrict__ normed,
    const u16* __restrict__ whi, const u16* __restrict__ wlo,
    const float* __restrict__ bgate,
    u16* __restrict__ qhi, u16* __restrict__ qlo, float* __restrict__ gate) {
  int ro = blockIdx.y * 64;
  int co = blockIdx.x * 64;             // 0..1023 (combined W rows)
  bool isGate = (co >= TQKV);
  const float* __restrict__ A = isGate ? x : normed;
  int tid = threadIdx.x;
  int w = tid >> 6, l = tid & 63;
  int l15 = l & 15, g = l >> 4;
  int srow = tid >> 2, sc = tid & 3;
  __shared__ u16 a_hi[64][72], a_lo[64][72];
  __shared__ u16 b_hi[64][72], b_lo[64][72];
  f32x4 acc[4] = {};
  for (int k0 = 0; k0 < Cc; k0 += 64) {
    __syncthreads();
    // stage A tile: fp32 -> split bf16
    #pragma unroll
    for (int q4 = 0; q4 < 4; q4++) {
      float4 f = *reinterpret_cast<const float4*>(
          &A[(size_t)(ro + srow) * Cc + k0 + 16 * sc + 4 * q4]);
      ushort4 h, lo;
      h.x = f2bf(f.x); lo.x = f2bf(f.x - bf2f(h.x));
      h.y = f2bf(f.y); lo.y = f2bf(f.y - bf2f(h.y));
      h.z = f2bf(f.z); lo.z = f2bf(f.z - bf2f(h.z));
      h.w = f2bf(f.w); lo.w = f2bf(f.w - bf2f(h.w));
      *reinterpret_cast<ushort4*>(&a_hi[srow][16 * sc + 4 * q4]) = h;
      *reinterpret_cast<ushort4*>(&a_lo[srow][16 * sc + 4 * q4]) = lo;
    }
    // stage W tile (pre-split u16)
    {
      size_t wb = (size_t)(co + srow) * Cc + k0 + 16 * sc;
      const uint4* sh = reinterpret_cast<const uint4*>(&whi[wb]);
      const uint4* sl = reinterpret_cast<const uint4*>(&wlo[wb]);
      *reinterpret_cast<uint4*>(&b_hi[srow][16 * sc]) = sh[0];
      *reinterpret_cast<uint4*>(&b_hi[srow][16 * sc + 8]) = sh[1];
      *reinterpret_cast<uint4*>(&b_lo[srow][16 * sc]) = sl[0];
      *reinterpret_cast<uint4*>(&b_lo[srow][16 * sc + 8]) = sl[1];
    }
    __syncthreads();
    #pragma unroll
    for (int ks = 0; ks < 2; ks++) {
      s16x8 wb_hi = *reinterpret_cast<const s16x8*>(&b_hi[16 * w + l15][8 * g + 32 * ks]);
      s16x8 wb_lo = *reinterpret_cast<const s16x8*>(&b_lo[16 * w + l15][8 * g + 32 * ks]);
      #pragma unroll
      for (int mt = 0; mt < 4; mt++) {
        s16x8 aa_hi = *reinterpret_cast<const s16x8*>(&a_hi[16 * mt + l15][8 * g + 32 * ks]);
        s16x8 aa_lo = *reinterpret_cast<const s16x8*>(&a_lo[16 * mt + l15][8 * g + 32 * ks]);
        acc[mt] = MFMA16(aa_hi, wb_hi, acc[mt], 0, 0, 0);
        acc[mt] = MFMA16(aa_hi, wb_lo, acc[mt], 0, 0, 0);
        acc[mt] = MFMA16(aa_lo, wb_hi, acc[mt], 0, 0, 0);
      }
    }
  }
  // epilogue: row = ro+16mt+4g+r, col = co+16w+l15
  if (!isGate) {
    int o = co + 16 * w + l15;
    #pragma unroll
    for (int mt = 0; mt < 4; mt++) {
      #pragma unroll
      for (int r = 0; r < 4; r++) {
        int row = ro + 16 * mt + 4 * g + r;
        float v = acc[mt][r];
        u16 hb = f2bf(v);
        qhi[(size_t)row * TQKV + o] = hb;
        qlo[(size_t)row * TQKV + o] = f2bf(v - bf2f(hb));
      }
    }
  } else {
    int o = co - TQKV + 16 * w + l15;
    float bg = bgate[o];
    #pragma unroll
    for (int mt = 0; mt < 4; mt++) {
      #pragma unroll
      for (int r = 0; r < 4; r++) {
        int row = ro + 16 * mt + 4 * g + r;
        float z = acc[mt][r] + bg;
        gate[(size_t)row * INNER + o] = 1.0f / (1.0f + __expf(-z));
      }
    }
  }
}

// ---------------------------------------------------------------------------
// Kernel 3: softmax stats via split-bf16 MFMA.
// Per (b,h, 64-wide i-strip): mm_i = m_i + log(sum_j exp(s_ij - m_i)).
// ---------------------------------------------------------------------------
__global__ __launch_bounds__(256) void stats_kernel(
    const u16* __restrict__ qhi, const u16* __restrict__ qlo,
    float* __restrict__ mmrow) {
  int bh = blockIdx.y;
  int b = bh >> 3, h = bh & 7;
  int i0 = blockIdx.x * 64;
  int tid = threadIdx.x;
  int w = tid >> 6;
  int l = tid & 63;
  int l15 = l & 15, g = l >> 4;
  __shared__ u16 q_hi[64][40], q_lo[64][40];
  __shared__ u16 k_hi[64][40], k_lo[64][40];
  __shared__ float red_m[4][64], red_l[4][64];

  int srow = tid >> 2, sc = tid & 3;
  {
    size_t gq = ((size_t)(b * Nn + i0 + srow)) * TQKV + h * Dd + 8 * sc;
    *reinterpret_cast<uint4*>(&q_hi[srow][8 * sc]) =
        *reinterpret_cast<const uint4*>(&qhi[gq]);
    *reinterpret_cast<uint4*>(&q_lo[srow][8 * sc]) =
        *reinterpret_cast<const uint4*>(&qlo[gq]);
  }
  __syncthreads();
  s16x8 bq_hi[4], bq_lo[4];
  #pragma unroll
  for (int nt = 0; nt < 4; nt++) {
    bq_hi[nt] = *reinterpret_cast<const s16x8*>(&q_hi[l15 + 16 * nt][8 * g]);
    bq_lo[nt] = *reinterpret_cast<const s16x8*>(&q_lo[l15 + 16 * nt][8 * g]);
  }
  float m[4], lsum[4];
  #pragma unroll
  for (int nt = 0; nt < 4; nt++) { m[nt] = -INFINITY; lsum[nt] = 0.f; }

  for (int jt = 0; jt < 32; jt++) {
    __syncthreads();
    size_t gk = ((size_t)(b * Nn + jt * 64 + srow)) * TQKV + INNER + h * Dd + 8 * sc;
    *reinterpret_cast<uint4*>(&k_hi[srow][8 * sc]) =
        *reinterpret_cast<const uint4*>(&qhi[gk]);
    *reinterpret_cast<uint4*>(&k_lo[srow][8 * sc]) =
        *reinterpret_cast<const uint4*>(&qlo[gk]);
    __syncthreads();
    s16x8 ka_hi = *reinterpret_cast<const s16x8*>(&k_hi[l15 + 16 * w][8 * g]);
    s16x8 ka_lo = *reinterpret_cast<const s16x8*>(&k_lo[l15 + 16 * w][8 * g]);
    #pragma unroll
    for (int nt = 0; nt < 4; nt++) {
      f32x4 acc = {0.f, 0.f, 0.f, 0.f};
      acc = MFMA16(ka_hi, bq_hi[nt], acc, 0, 0, 0);
      acc = MFMA16(ka_hi, bq_lo[nt], acc, 0, 0, 0);
      acc = MFMA16(ka_lo, bq_hi[nt], acc, 0, 0, 0);
      float mt = fmaxf(fmaxf(acc[0], acc[1]), fmaxf(acc[2], acc[3]));
      float mn = fmaxf(m[nt], mt);
      float ls = __expf(acc[0] - mn) + __expf(acc[1] - mn) +
                 __expf(acc[2] - mn) + __expf(acc[3] - mn);
      lsum[nt] = lsum[nt] * __expf(m[nt] - mn) + ls;
      m[nt] = mn;
    }
  }
  #pragma unroll
  for (int off = 16; off <= 32; off <<= 1) {
    #pragma unroll
    for (int nt = 0; nt < 4; nt++) {
      float mo = __shfl_xor(m[nt], off);
      float lo = __shfl_xor(lsum[nt], off);
      float mn = fmaxf(m[nt], mo);
      lsum[nt] = lsum[nt] * __expf(m[nt] - mn) + lo * __expf(mo - mn);
      m[nt] = mn;
    }
  }
  if (g == 0) {
    #pragma unroll
    for (int nt = 0; nt < 4; nt++) {
      red_m[w][l15 + 16 * nt] = m[nt];
      red_l[w][l15 + 16 * nt] = lsum[nt];
    }
  }
  __syncthreads();
  if (tid < 64) {
    float M = fmaxf(fmaxf(red_m[0][tid], red_m[1][tid]),
                    fmaxf(red_m[2][tid], red_m[3][tid]));
    float L = red_l[0][tid] * __expf(red_m[0][tid] - M)
            + red_l[1][tid] * __expf(red_m[1][tid] - M)
            + red_l[2][tid] * __expf(red_m[2][tid] - M)
            + red_l[3][tid] * __expf(red_m[3][tid] - M);
    mmrow[(size_t)bh * Nn + i0 + tid] = M + __logf(L);
  }
}

// ---------------------------------------------------------------------------
// Kernel 4: out[j,d] = sum_i exp(s_ij - mm_i) * v[i,d], times gate.
// Output written as split bf16 (feeds final MFMA GEMM).
// ---------------------------------------------------------------------------
__global__ __launch_bounds__(256) void attnout_kernel(
    const u16* __restrict__ qhi, const u16* __restrict__ qlo,
    const float* __restrict__ mmrow, const float* __restrict__ gate,
    u16* __restrict__ aohi, u16* __restrict__ aolo) {
  int bh = blockIdx.y;
  int b = bh >> 3, h = bh & 7;
  int j0 = blockIdx.x * 64;
  int tid = threadIdx.x;
  int w = tid >> 6;
  int l = tid & 63;
  int l15 = l & 15, g = l >> 4;
  __shared__ u16 k_hi[64][40], k_lo[64][40];
  __shared__ u16 q_hi[64][40], q_lo[64][40];
  __shared__ u16 vt_hi[32][72], vt_lo[32][72];
  __shared__ u16 p_hi[64][72], p_lo[64][72];
  __shared__ float mm_lds[64];

  int srow = tid >> 2, sc = tid & 3;
  {
    size_t gk = ((size_t)(b * Nn + j0 + srow)) * TQKV + INNER + h * Dd + 8 * sc;
    *reinterpret_cast<uint4*>(&k_hi[srow][8 * sc]) =
        *reinterpret_cast<const uint4*>(&qhi[gk]);
    *reinterpret_cast<uint4*>(&k_lo[srow][8 * sc]) =
        *reinterpret_cast<const uint4*>(&qlo[gk]);
  }
  __syncthreads();
  s16x8 kb_hi = *reinterpret_cast<const s16x8*>(&k_hi[l15 + 16 * w][8 * g]);
  s16x8 kb_lo = *reinterpret_cast<const s16x8*>(&k_lo[l15 + 16 * w][8 * g]);

  f32x4 accd0 = {0.f, 0.f, 0.f, 0.f};
  f32x4 accd1 = {0.f, 0.f, 0.f, 0.f};
  int xorv = 8 * (l15 >> 2);

  for (int it = 0; it < 32; it++) {
    int i0 = it * 64;
    __syncthreads();   // prev iter's LDS reads complete
    size_t gq = ((size_t)(b * Nn + i0 + srow)) * TQKV + h * Dd + 8 * sc;
    *reinterpret_cast<uint4*>(&q_hi[srow][8 * sc]) =
        *reinterpret_cast<const uint4*>(&qhi[gq]);
    *reinterpret_cast<uint4*>(&q_lo[srow][8 * sc]) =
        *reinterpret_cast<const uint4*>(&qlo[gq]);
    size_t gv = gq + 2 * INNER;
    uint4 vh4 = *reinterpret_cast<const uint4*>(&qhi[gv]);
    uint4 vl4 = *reinterpret_cast<const uint4*>(&qlo[gv]);
    const u16* vhp = reinterpret_cast<const u16*>(&vh4);
    const u16* vlp = reinterpret_cast<const u16*>(&vl4);
    #pragma unroll
    for (int e = 0; e < 8; e++) {
      int d = 8 * sc + e;
      int col = srow ^ (8 * ((d >> 2) & 3));
      vt_hi[d][col] = vhp[e];
      vt_lo[d][col] = vlp[e];
    }
    if (tid < 64) mm_lds[tid] = mmrow[(size_t)bh * Nn + i0 + tid];
    __syncthreads();
    #pragma unroll
    for (int mt = 0; mt < 4; mt++) {
      s16x8 qa_hi = *reinterpret_cast<const s16x8*>(&q_hi[l15 + 16 * mt][8 * g]);
      s16x8 qa_lo = *reinterpret_cast<const s16x8*>(&q_lo[l15 + 16 * mt][8 * g]);
      f32x4 s = {0.f, 0.f, 0.f, 0.f};
      s = MFMA16(qa_hi, kb_hi, s, 0, 0, 0);
      s = MFMA16(qa_hi, kb_lo, s, 0, 0, 0);
      s = MFMA16(qa_lo, kb_hi, s, 0, 0, 0);
      int ib = 16 * mt + 4 * g;
      u16 ph[4], pl[4];
      #pragma unroll
      for (int r = 0; r < 4; r++) {
        float p = __expf(s[r] - mm_lds[ib + r]);
        u16 hb = f2bf(p);
        ph[r] = hb;
        pl[r] = f2bf(p - bf2f(hb));
      }
      ushort4 t1 = make_ushort4(ph[0], ph[1], ph[2], ph[3]);
      *reinterpret_cast<ushort4*>(&p_hi[l15 + 16 * w][ib]) = t1;
      ushort4 t2 = make_ushort4(pl[0], pl[1], pl[2], pl[3]);
      *reinterpret_cast<ushort4*>(&p_lo[l15 + 16 * w][ib]) = t2;
    }
    __syncthreads();
    #pragma unroll
    for (int ks = 0; ks < 2; ks++) {
      s16x8 pa_hi = *reinterpret_cast<const s16x8*>(&p_hi[l15 + 16 * w][8 * g + 32 * ks]);
      s16x8 pa_lo = *reinterpret_cast<const s16x8*>(&p_lo[l15 + 16 * w][8 * g + 32 * ks]);
      int col = (8 * g + 32 * ks) ^ xorv;
      {
        s16x8 vb_hi = *reinterpret_cast<const s16x8*>(&vt_hi[l15][col]);
        s16x8 vb_lo = *reinterpret_cast<const s16x8*>(&vt_lo[l15][col]);
        accd0 = MFMA16(pa_hi, vb_hi, accd0, 0, 0, 0);
        accd0 = MFMA16(pa_hi, vb_lo, accd0, 0, 0, 0);
        accd0 = MFMA16(pa_lo, vb_hi, accd0, 0, 0, 0);
      }
      {
        s16x8 vb_hi = *reinterpret_cast<const s16x8*>(&vt_hi[l15 + 16][col]);
        s16x8 vb_lo = *reinterpret_cast<const s16x8*>(&vt_lo[l15 + 16][col]);
        accd1 = MFMA16(pa_hi, vb_hi, accd1, 0, 0, 0);
        accd1 = MFMA16(pa_hi, vb_lo, accd1, 0, 0, 0);
        accd1 = MFMA16(pa_lo, vb_hi, accd1, 0, 0, 0);
      }
    }
  }
  #pragma unroll
  for (int r = 0; r < 4; r++) {
    int j = j0 + 16 * w + 4 * g + r;
    size_t rowb = ((size_t)(b * Nn + j)) * INNER + h * Dd;
    size_t i0x = rowb + l15;
    float v0 = accd0[r] * gate[i0x];
    u16 h0 = f2bf(v0);
    aohi[i0x] = h0;
    aolo[i0x] = f2bf(v0 - bf2f(h0));
    size_t i1x = rowb + l15 + 16;
    float v1 = accd1[r] * gate[i1x];
    u16 h1 = f2bf(v1);
    aohi[i1x] = h1;
    aolo[i1x] = f2bf(v1 - bf2f(h1));
  }
}

// ---------------------------------------------------------------------------
// Kernel 5: y = x + ao @ W_final^T + b_final via split-bf16 MFMA.
// ---------------------------------------------------------------------------
__global__ __launch_bounds__(256) void final_kernel(
    const u16* __restrict__ aohi, const u16* __restrict__ aolo,
    const u16* __restrict__ wfhi, const u16* __restrict__ wflo,
    const float* __restrict__ bf, const float* __restrict__ x,
    float* __restrict__ out) {
  int ro = blockIdx.y * 64;
  int co = blockIdx.x * 64;   // 0..255
  int tid = threadIdx.x;
  int w = tid >> 6, l = tid & 63;
  int l15 = l & 15, g = l >> 4;
  int srow = tid >> 2, sc = tid & 3;
  __shared__ u16 a_hi[64][72], a_lo[64][72];
  __shared__ u16 b_hi[64][72], b_lo[64][72];
  f32x4 acc[4] = {};
  for (int k0 = 0; k0 < INNER; k0 += 64) {
    __syncthreads();
    {
      size_t ab = (size_t)(ro + srow) * INNER + k0 + 16 * sc;
      const uint4* sh = reinterpret_cast<const uint4*>(&aohi[ab]);
      const uint4* sl = reinterpret_cast<const uint4*>(&aolo[ab]);
      *reinterpret_cast<uint4*>(&a_hi[srow][16 * sc]) = sh[0];
      *reinterpret_cast<uint4*>(&a_hi[srow][16 * sc + 8]) = sh[1];
      *reinterpret_cast<uint4*>(&a_lo[srow][16 * sc]) = sl[0];
      *reinterpret_cast<uint4*>(&a_lo[srow][16 * sc + 8]) = sl[1];
      size_t wb = (size_t)(co + srow) * Cc + k0 + 16 * sc;
      const uint4* th = reinterpret_cast<const uint4*>(&wfhi[wb]);
      const uint4* tl = reinterpret_cast<const uint4*>(&wflo[wb]);
      *reinterpret_cast<uint4*>(&b_hi[srow][16 * sc]) = th[0];
      *reinterpret_cast<uint4*>(&b_hi[srow][16 * sc + 8]) = th[1];
      *reinterpret_cast<uint4*>(&b_lo[srow][16 * sc]) = tl[0];
      *reinterpret_cast<uint4*>(&b_lo[srow][16 * sc + 8]) = tl[1];
    }
    __syncthreads();
    #pragma unroll
    for (int ks = 0; ks < 2; ks++) {
      s16x8 wb_hi = *reinterpret_cast<const s16x8*>(&b_hi[16 * w + l15][8 * g + 32 * ks]);
      s16x8 wb_lo = *reinterpret_cast<const s16x8*>(&b_lo[16 * w + l15][8 * g + 32 * ks]);
      #pragma unroll
      for (int mt = 0; mt < 4; mt++) {
        s16x8 aa_hi = *reinterpret_cast<const s16x8*>(&a_hi[16 * mt + l15][8 * g + 32 * ks]);
        s16x8 aa_lo = *reinterpret_cast<const s16x8*>(&a_lo[16 * mt + l15][8 * g + 32 * ks]);
        acc[mt] = MFMA16(aa_hi, wb_hi, acc[mt], 0, 0, 0);
        acc[mt] = MFMA16(aa_hi, wb_lo, acc[mt], 0, 0, 0);
        acc[mt] = MFMA16(aa_lo, wb_hi, acc[mt], 0, 0, 0);
      }
    }
  }
  int o = co + 16 * w + l15;
  float bfo = bf[o];
  #pragma unroll
  for (int mt = 0; mt < 4; mt++) {
    #pragma unroll
    for (int r = 0; r < 4; r++) {
      int row = ro + 16 * mt + 4 * g + r;
      out[(size_t)row * Cc + o] = x[(size_t)row * Cc + o] + acc[mt][r] + bfo;
    }
  }
}

// ---------------------------------------------------------------------------
extern "C" void kernel_launch(void* const* d_in, const int* in_sizes, int n_in,
                              void* d_out, int out_size, void* d_ws, size_t ws_size,
                              hipStream_t stream) {
  (void)in_sizes; (void)n_in; (void)out_size; (void)ws_size;
  const float* x     = (const float*)d_in[0];
  const float* gam   = (const float*)d_in[1];
  const float* bet   = (const float*)d_in[2];
  const float* Wqkv  = (const float*)d_in[3];
  const float* Wgate = (const float*)d_in[4];
  const float* bgate = (const float*)d_in[5];
  const float* Wf    = (const float*)d_in[6];
  const float* bf    = (const float*)d_in[7];
  float* out = (float*)d_out;
  float* ws  = (float*)d_ws;

  float* normed = ws + OFF_NORMED;
  float* gatep  = ws + OFF_GATE;
  float* mm     = ws + OFF_MM;
  u16*   qhi    = (u16*)(ws + OFF_QHI);
  u16*   qlo    = (u16*)(ws + OFF_QLO);
  u16*   whi    = (u16*)(ws + OFF_WHI);
  u16*   wlo    = (u16*)(ws + OFF_WLO);
  u16*   aohi   = (u16*)(ws + OFF_AOHI);   // aliases normed (dead after proj)
  u16*   aolo   = (u16*)(ws + OFF_AOLO);

  ln_kernel<<<NROWS, 256, 0, stream>>>(x, gam, bet, normed);
  wconv_kernel<<<1280, 256, 0, stream>>>(Wqkv, Wgate, Wf, whi, wlo);
  proj_kernel<<<dim3(16, 64), 256, 0, stream>>>(x, normed, whi, wlo, bgate,
                                                qhi, qlo, gatep);
  stats_kernel<<<dim3(32, 16), 256, 0, stream>>>(qhi, qlo, mm);
  attnout_kernel<<<dim3(32, 16), 256, 0, stream>>>(qhi, qlo, mm, gatep,
                                                   aohi, aolo);
  final_kernel<<<dim3(4, 64), 256, 0, stream>>>(aohi, aolo,
                                                whi + 1024 * Cc, wlo + 1024 * Cc,
                                                bf, x, out);
}

// Round 6
// 188.053 us; speedup vs baseline: 2.5499x; 1.0593x over previous
//
#include <hip/hip_runtime.h>
#include <math.h>

// Problem constants (B=2, N=2048, C=256, H=8, D=32)
#define Bb 2
#define Nn 2048
#define Cc 256
#define Hh 8
#define Dd 32
#define INNER 256           // H*D
#define TQKV 768            // 3*INNER
#define NROWS 4096          // B*N
#define EPSf 1e-5f
#define SCALEf 0.17677669529663687f  // 1/sqrt(32)

typedef unsigned short u16;
typedef short s16x8 __attribute__((ext_vector_type(8)));
typedef float f32x4 __attribute__((ext_vector_type(4)));
#define MFMA16 __builtin_amdgcn_mfma_f32_16x16x32_bf16

// workspace layout (float offsets); total 5,603,328 floats = 22.4 MB
#define OFF_NORMED 0u          // [4096][256] f32   (dead after proj)
#define OFF_AOHI   0u          // [4096][256] u16   (aliases normed)
#define OFF_AOLO   524288u     // [4096][256] u16   (aliases normed)
#define OFF_GATE   1048576u    // [4096][256] f32 (sigmoid applied)
#define OFF_MM     2097152u    // [16][2048] f32:  m_i + log(l_i)
#define OFF_QHI    2129920u    // [4096][768] bf16 (as u16)
#define OFF_QLO    3702784u    // [4096][768] bf16 (as u16)
#define OFF_WHI    5275648u    // [1280][256] u16: Wqkv(Q-scaled) | Wgate | Wf
#define OFF_WLO    5439488u    // [1280][256] u16

// bf16 helpers (RNE)
__device__ inline u16 f2bf(float f) {
  union { float f; unsigned u; } v; v.f = f;
  unsigned r = v.u + 0x7fffu + ((v.u >> 16) & 1u);
  return (u16)(r >> 16);
}
__device__ inline float bf2f(u16 h) {
  union { unsigned u; float f; } v; v.u = ((unsigned)h) << 16;
  return v.f;
}

// ---------------------------------------------------------------------------
// Kernel 1: LayerNorm (biased variance)
// ---------------------------------------------------------------------------
__global__ __launch_bounds__(256) void ln_kernel(
    const float* __restrict__ x, const float* __restrict__ gam,
    const float* __restrict__ bet, float* __restrict__ normed) {
  int row = blockIdx.x;
  int tid = threadIdx.x;
  size_t base = (size_t)row * Cc;
  float v = x[base + tid];
  float s1 = v, s2 = v * v;
  #pragma unroll
  for (int off = 32; off; off >>= 1) {
    s1 += __shfl_xor(s1, off);
    s2 += __shfl_xor(s2, off);
  }
  __shared__ float w1[4], w2[4];
  if ((tid & 63) == 0) { w1[tid >> 6] = s1; w2[tid >> 6] = s2; }
  __syncthreads();
  s1 = w1[0] + w1[1] + w1[2] + w1[3];
  s2 = w2[0] + w2[1] + w2[2] + w2[3];
  float mu = s1 * (1.0f / Cc);
  float var = s2 * (1.0f / Cc) - mu * mu;
  float rstd = rsqrtf(var + EPSf);
  normed[base + tid] = (v - mu) * rstd * gam[tid] + bet[tid];
}

// ---------------------------------------------------------------------------
// Kernel 1b: weight split-bf16 conversion.
// ---------------------------------------------------------------------------
__global__ __launch_bounds__(256) void wconv_kernel(
    const float* __restrict__ Wqkv, const float* __restrict__ Wgate,
    const float* __restrict__ Wf, u16* __restrict__ whi, u16* __restrict__ wlo) {
  int row = blockIdx.x;
  int col = threadIdx.x;
  float v;
  if (row < TQKV) {
    v = Wqkv[(size_t)row * Cc + col];
    if (row < INNER) v *= SCALEf;   // fold attention scale into Q weights
  } else if (row < TQKV + INNER) {
    v = Wgate[(size_t)(row - TQKV) * Cc + col];
  } else {
    v = Wf[(size_t)(row - TQKV - INNER) * Cc + col];
  }
  u16 h = f2bf(v);
  whi[(size_t)row * Cc + col] = h;
  wlo[(size_t)row * Cc + col] = f2bf(v - bf2f(h));
}

// ---------------------------------------------------------------------------
// Kernel 2: fused projections via split-bf16 MFMA.
// ---------------------------------------------------------------------------
__global__ __launch_bounds__(256) void proj_kernel(
    const float* __restrict__ x, const float* __restrict__ normed,
    const u16* __restrict__ whi, const u16* __restrict__ wlo,
    const float* __restrict__ bgate,
    u16* __restrict__ qhi, u16* __restrict__ qlo, float* __restrict__ gate) {
  int ro = blockIdx.y * 64;
  int co = blockIdx.x * 64;             // 0..1023 (combined W rows)
  bool isGate = (co >= TQKV);
  const float* __restrict__ A = isGate ? x : normed;
  int tid = threadIdx.x;
  int w = tid >> 6, l = tid & 63;
  int l15 = l & 15, g = l >> 4;
  int srow = tid >> 2, sc = tid & 3;
  __shared__ u16 a_hi[64][72], a_lo[64][72];
  __shared__ u16 b_hi[64][72], b_lo[64][72];
  f32x4 acc[4] = {};
  for (int k0 = 0; k0 < Cc; k0 += 64) {
    __syncthreads();
    // stage A tile: fp32 -> split bf16
    #pragma unroll
    for (int q4 = 0; q4 < 4; q4++) {
      float4 f = *reinterpret_cast<const float4*>(
          &A[(size_t)(ro + srow) * Cc + k0 + 16 * sc + 4 * q4]);
      ushort4 h, lo;
      h.x = f2bf(f.x); lo.x = f2bf(f.x - bf2f(h.x));
      h.y = f2bf(f.y); lo.y = f2bf(f.y - bf2f(h.y));
      h.z = f2bf(f.z); lo.z = f2bf(f.z - bf2f(h.z));
      h.w = f2bf(f.w); lo.w = f2bf(f.w - bf2f(h.w));
      *reinterpret_cast<ushort4*>(&a_hi[srow][16 * sc + 4 * q4]) = h;
      *reinterpret_cast<ushort4*>(&a_lo[srow][16 * sc + 4 * q4]) = lo;
    }
    // stage W tile (pre-split u16)
    {
      size_t wb = (size_t)(co + srow) * Cc + k0 + 16 * sc;
      const uint4* sh = reinterpret_cast<const uint4*>(&whi[wb]);
      const uint4* sl = reinterpret_cast<const uint4*>(&wlo[wb]);
      *reinterpret_cast<uint4*>(&b_hi[srow][16 * sc]) = sh[0];
      *reinterpret_cast<uint4*>(&b_hi[srow][16 * sc + 8]) = sh[1];
      *reinterpret_cast<uint4*>(&b_lo[srow][16 * sc]) = sl[0];
      *reinterpret_cast<uint4*>(&b_lo[srow][16 * sc + 8]) = sl[1];
    }
    __syncthreads();
    #pragma unroll
    for (int ks = 0; ks < 2; ks++) {
      s16x8 wb_hi = *reinterpret_cast<const s16x8*>(&b_hi[16 * w + l15][8 * g + 32 * ks]);
      s16x8 wb_lo = *reinterpret_cast<const s16x8*>(&b_lo[16 * w + l15][8 * g + 32 * ks]);
      #pragma unroll
      for (int mt = 0; mt < 4; mt++) {
        s16x8 aa_hi = *reinterpret_cast<const s16x8*>(&a_hi[16 * mt + l15][8 * g + 32 * ks]);
        s16x8 aa_lo = *reinterpret_cast<const s16x8*>(&a_lo[16 * mt + l15][8 * g + 32 * ks]);
        acc[mt] = MFMA16(aa_hi, wb_hi, acc[mt], 0, 0, 0);
        acc[mt] = MFMA16(aa_hi, wb_lo, acc[mt], 0, 0, 0);
        acc[mt] = MFMA16(aa_lo, wb_hi, acc[mt], 0, 0, 0);
      }
    }
  }
  // epilogue: row = ro+16mt+4g+r, col = co+16w+l15
  if (!isGate) {
    int o = co + 16 * w + l15;
    #pragma unroll
    for (int mt = 0; mt < 4; mt++) {
      #pragma unroll
      for (int r = 0; r < 4; r++) {
        int row = ro + 16 * mt + 4 * g + r;
        float v = acc[mt][r];
        u16 hb = f2bf(v);
        qhi[(size_t)row * TQKV + o] = hb;
        qlo[(size_t)row * TQKV + o] = f2bf(v - bf2f(hb));
      }
    }
  } else {
    int o = co - TQKV + 16 * w + l15;
    float bg = bgate[o];
    #pragma unroll
    for (int mt = 0; mt < 4; mt++) {
      #pragma unroll
      for (int r = 0; r < 4; r++) {
        int row = ro + 16 * mt + 4 * g + r;
        float z = acc[mt][r] + bg;
        gate[(size_t)row * INNER + o] = 1.0f / (1.0f + __expf(-z));
      }
    }
  }
}

// ---------------------------------------------------------------------------
// Kernel 3: softmax stats via split-bf16 MFMA (T14: K prefetched into regs
// during compute of the previous tile).
// ---------------------------------------------------------------------------
__global__ __launch_bounds__(256) void stats_kernel(
    const u16* __restrict__ qhi, const u16* __restrict__ qlo,
    float* __restrict__ mmrow) {
  int bh = blockIdx.y;
  int b = bh >> 3, h = bh & 7;
  int i0 = blockIdx.x * 64;
  int tid = threadIdx.x;
  int w = tid >> 6;
  int l = tid & 63;
  int l15 = l & 15, g = l >> 4;
  __shared__ u16 q_hi[64][40], q_lo[64][40];
  __shared__ u16 k_hi[64][40], k_lo[64][40];
  __shared__ float red_m[4][64], red_l[4][64];

  int srow = tid >> 2, sc = tid & 3;
  {
    size_t gq = ((size_t)(b * Nn + i0 + srow)) * TQKV + h * Dd + 8 * sc;
    *reinterpret_cast<uint4*>(&q_hi[srow][8 * sc]) =
        *reinterpret_cast<const uint4*>(&qhi[gq]);
    *reinterpret_cast<uint4*>(&q_lo[srow][8 * sc]) =
        *reinterpret_cast<const uint4*>(&qlo[gq]);
  }
  // prefetch K tile 0 into registers
  size_t gk0 = ((size_t)(b * Nn + srow)) * TQKV + INNER + h * Dd + 8 * sc;
  uint4 pk_h = *reinterpret_cast<const uint4*>(&qhi[gk0]);
  uint4 pk_l = *reinterpret_cast<const uint4*>(&qlo[gk0]);
  __syncthreads();
  s16x8 bq_hi[4], bq_lo[4];
  #pragma unroll
  for (int nt = 0; nt < 4; nt++) {
    bq_hi[nt] = *reinterpret_cast<const s16x8*>(&q_hi[l15 + 16 * nt][8 * g]);
    bq_lo[nt] = *reinterpret_cast<const s16x8*>(&q_lo[l15 + 16 * nt][8 * g]);
  }
  float m[4], lsum[4];
  #pragma unroll
  for (int nt = 0; nt < 4; nt++) { m[nt] = -INFINITY; lsum[nt] = 0.f; }

  for (int jt = 0; jt < 32; jt++) {
    __syncthreads();   // prev MFMA readers done with k_lds
    *reinterpret_cast<uint4*>(&k_hi[srow][8 * sc]) = pk_h;
    *reinterpret_cast<uint4*>(&k_lo[srow][8 * sc]) = pk_l;
    if (jt < 31) {  // issue next-tile loads; land during this tile's MFMA
      size_t gk = ((size_t)(b * Nn + (jt + 1) * 64 + srow)) * TQKV + INNER + h * Dd + 8 * sc;
      pk_h = *reinterpret_cast<const uint4*>(&qhi[gk]);
      pk_l = *reinterpret_cast<const uint4*>(&qlo[gk]);
    }
    __syncthreads();
    s16x8 ka_hi = *reinterpret_cast<const s16x8*>(&k_hi[l15 + 16 * w][8 * g]);
    s16x8 ka_lo = *reinterpret_cast<const s16x8*>(&k_lo[l15 + 16 * w][8 * g]);
    #pragma unroll
    for (int nt = 0; nt < 4; nt++) {
      f32x4 acc = {0.f, 0.f, 0.f, 0.f};
      acc = MFMA16(ka_hi, bq_hi[nt], acc, 0, 0, 0);
      acc = MFMA16(ka_hi, bq_lo[nt], acc, 0, 0, 0);
      acc = MFMA16(ka_lo, bq_hi[nt], acc, 0, 0, 0);
      float mt = fmaxf(fmaxf(acc[0], acc[1]), fmaxf(acc[2], acc[3]));
      float mn = fmaxf(m[nt], mt);
      float ls = __expf(acc[0] - mn) + __expf(acc[1] - mn) +
                 __expf(acc[2] - mn) + __expf(acc[3] - mn);
      lsum[nt] = lsum[nt] * __expf(m[nt] - mn) + ls;
      m[nt] = mn;
    }
  }
  #pragma unroll
  for (int off = 16; off <= 32; off <<= 1) {
    #pragma unroll
    for (int nt = 0; nt < 4; nt++) {
      float mo = __shfl_xor(m[nt], off);
      float lo = __shfl_xor(lsum[nt], off);
      float mn = fmaxf(m[nt], mo);
      lsum[nt] = lsum[nt] * __expf(m[nt] - mn) + lo * __expf(mo - mn);
      m[nt] = mn;
    }
  }
  if (g == 0) {
    #pragma unroll
    for (int nt = 0; nt < 4; nt++) {
      red_m[w][l15 + 16 * nt] = m[nt];
      red_l[w][l15 + 16 * nt] = lsum[nt];
    }
  }
  __syncthreads();
  if (tid < 64) {
    float M = fmaxf(fmaxf(red_m[0][tid], red_m[1][tid]),
                    fmaxf(red_m[2][tid], red_m[3][tid]));
    float L = red_l[0][tid] * __expf(red_m[0][tid] - M)
            + red_l[1][tid] * __expf(red_m[1][tid] - M)
            + red_l[2][tid] * __expf(red_m[2][tid] - M)
            + red_l[3][tid] * __expf(red_m[3][tid] - M);
    mmrow[(size_t)bh * Nn + i0 + tid] = M + __logf(L);
  }
}

// ---------------------------------------------------------------------------
// Kernel 4: out[j,d] = sum_i exp(s_ij - mm_i) * v[i,d], times gate.
// Pitch 74 (odd word count) kills the 8-way conflicts on vt/p; Q/V/mm
// prefetched into registers during the previous tile's compute (T14).
// ---------------------------------------------------------------------------
__global__ __launch_bounds__(256) void attnout_kernel(
    const u16* __restrict__ qhi, const u16* __restrict__ qlo,
    const float* __restrict__ mmrow, const float* __restrict__ gate,
    u16* __restrict__ aohi, u16* __restrict__ aolo) {
  int bh = blockIdx.y;
  int b = bh >> 3, h = bh & 7;
  int j0 = blockIdx.x * 64;
  int tid = threadIdx.x;
  int w = tid >> 6;
  int l = tid & 63;
  int l15 = l & 15, g = l >> 4;
  __shared__ u16 k_hi[64][40], k_lo[64][40];
  __shared__ u16 q_hi[64][40], q_lo[64][40];
  __shared__ u16 vt_hi[32][74], vt_lo[32][74];
  __shared__ u16 p_hi[64][74], p_lo[64][74];
  __shared__ float mm_lds[64];

  int srow = tid >> 2, sc = tid & 3;
  {
    size_t gk = ((size_t)(b * Nn + j0 + srow)) * TQKV + INNER + h * Dd + 8 * sc;
    *reinterpret_cast<uint4*>(&k_hi[srow][8 * sc]) =
        *reinterpret_cast<const uint4*>(&qhi[gk]);
    *reinterpret_cast<uint4*>(&k_lo[srow][8 * sc]) =
        *reinterpret_cast<const uint4*>(&qlo[gk]);
  }
  // prefetch tile 0 (Q, V, mm) into registers
  size_t gq0 = ((size_t)(b * Nn + srow)) * TQKV + h * Dd + 8 * sc;
  uint4 pq_h = *reinterpret_cast<const uint4*>(&qhi[gq0]);
  uint4 pq_l = *reinterpret_cast<const uint4*>(&qlo[gq0]);
  uint4 pv_h = *reinterpret_cast<const uint4*>(&qhi[gq0 + 2 * INNER]);
  uint4 pv_l = *reinterpret_cast<const uint4*>(&qlo[gq0 + 2 * INNER]);
  float pmm = 0.f;
  if (tid < 64) pmm = mmrow[(size_t)bh * Nn + tid];
  __syncthreads();
  s16x8 kb_hi = *reinterpret_cast<const s16x8*>(&k_hi[l15 + 16 * w][8 * g]);
  s16x8 kb_lo = *reinterpret_cast<const s16x8*>(&k_lo[l15 + 16 * w][8 * g]);

  f32x4 accd0 = {0.f, 0.f, 0.f, 0.f};
  f32x4 accd1 = {0.f, 0.f, 0.f, 0.f};
  int xorv = 8 * (l15 >> 2);

  for (int it = 0; it < 32; it++) {
    __syncthreads();   // prev iter's LDS readers complete
    // write prefetched tile to LDS
    *reinterpret_cast<uint4*>(&q_hi[srow][8 * sc]) = pq_h;
    *reinterpret_cast<uint4*>(&q_lo[srow][8 * sc]) = pq_l;
    {
      const u16* vhp = reinterpret_cast<const u16*>(&pv_h);
      const u16* vlp = reinterpret_cast<const u16*>(&pv_l);
      #pragma unroll
      for (int e = 0; e < 8; e++) {
        int d = 8 * sc + e;
        int col = srow ^ (8 * ((d >> 2) & 3));
        vt_hi[d][col] = vhp[e];
        vt_lo[d][col] = vlp[e];
      }
    }
    if (tid < 64) mm_lds[tid] = pmm;
    // issue next-tile loads; they land during this tile's MFMA/exp work
    if (it < 31) {
      size_t gq = ((size_t)(b * Nn + (it + 1) * 64 + srow)) * TQKV + h * Dd + 8 * sc;
      pq_h = *reinterpret_cast<const uint4*>(&qhi[gq]);
      pq_l = *reinterpret_cast<const uint4*>(&qlo[gq]);
      pv_h = *reinterpret_cast<const uint4*>(&qhi[gq + 2 * INNER]);
      pv_l = *reinterpret_cast<const uint4*>(&qlo[gq + 2 * INNER]);
      if (tid < 64) pmm = mmrow[(size_t)bh * Nn + (it + 1) * 64 + tid];
    }
    __syncthreads();
    // QK^T + exp + split + store P[j][i]
    #pragma unroll
    for (int mt = 0; mt < 4; mt++) {
      s16x8 qa_hi = *reinterpret_cast<const s16x8*>(&q_hi[l15 + 16 * mt][8 * g]);
      s16x8 qa_lo = *reinterpret_cast<const s16x8*>(&q_lo[l15 + 16 * mt][8 * g]);
      f32x4 s = {0.f, 0.f, 0.f, 0.f};
      s = MFMA16(qa_hi, kb_hi, s, 0, 0, 0);
      s = MFMA16(qa_hi, kb_lo, s, 0, 0, 0);
      s = MFMA16(qa_lo, kb_hi, s, 0, 0, 0);
      int ib = 16 * mt + 4 * g;
      u16 ph[4], pl[4];
      #pragma unroll
      for (int r = 0; r < 4; r++) {
        float p = __expf(s[r] - mm_lds[ib + r]);
        u16 hb = f2bf(p);
        ph[r] = hb;
        pl[r] = f2bf(p - bf2f(hb));
      }
      ushort4 t1 = make_ushort4(ph[0], ph[1], ph[2], ph[3]);
      *reinterpret_cast<ushort4*>(&p_hi[l15 + 16 * w][ib]) = t1;
      ushort4 t2 = make_ushort4(pl[0], pl[1], pl[2], pl[3]);
      *reinterpret_cast<ushort4*>(&p_lo[l15 + 16 * w][ib]) = t2;
    }
    __syncthreads();
    // PV: D[m=j][n=d] += sum_i P^T[j,i] V[i,d]
    #pragma unroll
    for (int ks = 0; ks < 2; ks++) {
      s16x8 pa_hi = *reinterpret_cast<const s16x8*>(&p_hi[l15 + 16 * w][8 * g + 32 * ks]);
      s16x8 pa_lo = *reinterpret_cast<const s16x8*>(&p_lo[l15 + 16 * w][8 * g + 32 * ks]);
      int col = (8 * g + 32 * ks) ^ xorv;
      {
        s16x8 vb_hi = *reinterpret_cast<const s16x8*>(&vt_hi[l15][col]);
        s16x8 vb_lo = *reinterpret_cast<const s16x8*>(&vt_lo[l15][col]);
        accd0 = MFMA16(pa_hi, vb_hi, accd0, 0, 0, 0);
        accd0 = MFMA16(pa_hi, vb_lo, accd0, 0, 0, 0);
        accd0 = MFMA16(pa_lo, vb_hi, accd0, 0, 0, 0);
      }
      {
        s16x8 vb_hi = *reinterpret_cast<const s16x8*>(&vt_hi[l15 + 16][col]);
        s16x8 vb_lo = *reinterpret_cast<const s16x8*>(&vt_lo[l15 + 16][col]);
        accd1 = MFMA16(pa_hi, vb_hi, accd1, 0, 0, 0);
        accd1 = MFMA16(pa_hi, vb_lo, accd1, 0, 0, 0);
        accd1 = MFMA16(pa_lo, vb_hi, accd1, 0, 0, 0);
      }
    }
  }
  #pragma unroll
  for (int r = 0; r < 4; r++) {
    int j = j0 + 16 * w + 4 * g + r;
    size_t rowb = ((size_t)(b * Nn + j)) * INNER + h * Dd;
    size_t i0x = rowb + l15;
    float v0 = accd0[r] * gate[i0x];
    u16 h0 = f2bf(v0);
    aohi[i0x] = h0;
    aolo[i0x] = f2bf(v0 - bf2f(h0));
    size_t i1x = rowb + l15 + 16;
    float v1 = accd1[r] * gate[i1x];
    u16 h1 = f2bf(v1);
    aohi[i1x] = h1;
    aolo[i1x] = f2bf(v1 - bf2f(h1));
  }
}

// ---------------------------------------------------------------------------
// Kernel 5: y = x + ao @ W_final^T + b_final via split-bf16 MFMA.
// ---------------------------------------------------------------------------
__global__ __launch_bounds__(256) void final_kernel(
    const u16* __restrict__ aohi, const u16* __restrict__ aolo,
    const u16* __restrict__ wfhi, const u16* __restrict__ wflo,
    const float* __restrict__ bf, const float* __restrict__ x,
    float* __restrict__ out) {
  int ro = blockIdx.y * 64;
  int co = blockIdx.x * 64;   // 0..255
  int tid = threadIdx.x;
  int w = tid >> 6, l = tid & 63;
  int l15 = l & 15, g = l >> 4;
  int srow = tid >> 2, sc = tid & 3;
  __shared__ u16 a_hi[64][72], a_lo[64][72];
  __shared__ u16 b_hi[64][72], b_lo[64][72];
  f32x4 acc[4] = {};
  for (int k0 = 0; k0 < INNER; k0 += 64) {
    __syncthreads();
    {
      size_t ab = (size_t)(ro + srow) * INNER + k0 + 16 * sc;
      const uint4* sh = reinterpret_cast<const uint4*>(&aohi[ab]);
      const uint4* sl = reinterpret_cast<const uint4*>(&aolo[ab]);
      *reinterpret_cast<uint4*>(&a_hi[srow][16 * sc]) = sh[0];
      *reinterpret_cast<uint4*>(&a_hi[srow][16 * sc + 8]) = sh[1];
      *reinterpret_cast<uint4*>(&a_lo[srow][16 * sc]) = sl[0];
      *reinterpret_cast<uint4*>(&a_lo[srow][16 * sc + 8]) = sl[1];
      size_t wb = (size_t)(co + srow) * Cc + k0 + 16 * sc;
      const uint4* th = reinterpret_cast<const uint4*>(&wfhi[wb]);
      const uint4* tl = reinterpret_cast<const uint4*>(&wflo[wb]);
      *reinterpret_cast<uint4*>(&b_hi[srow][16 * sc]) = th[0];
      *reinterpret_cast<uint4*>(&b_hi[srow][16 * sc + 8]) = th[1];
      *reinterpret_cast<uint4*>(&b_lo[srow][16 * sc]) = tl[0];
      *reinterpret_cast<uint4*>(&b_lo[srow][16 * sc + 8]) = tl[1];
    }
    __syncthreads();
    #pragma unroll
    for (int ks = 0; ks < 2; ks++) {
      s16x8 wb_hi = *reinterpret_cast<const s16x8*>(&b_hi[16 * w + l15][8 * g + 32 * ks]);
      s16x8 wb_lo = *reinterpret_cast<const s16x8*>(&b_lo[16 * w + l15][8 * g + 32 * ks]);
      #pragma unroll
      for (int mt = 0; mt < 4; mt++) {
        s16x8 aa_hi = *reinterpret_cast<const s16x8*>(&a_hi[16 * mt + l15][8 * g + 32 * ks]);
        s16x8 aa_lo = *reinterpret_cast<const s16x8*>(&a_lo[16 * mt + l15][8 * g + 32 * ks]);
        acc[mt] = MFMA16(aa_hi, wb_hi, acc[mt], 0, 0, 0);
        acc[mt] = MFMA16(aa_hi, wb_lo, acc[mt], 0, 0, 0);
        acc[mt] = MFMA16(aa_lo, wb_hi, acc[mt], 0, 0, 0);
      }
    }
  }
  int o = co + 16 * w + l15;
  float bfo = bf[o];
  #pragma unroll
  for (int mt = 0; mt < 4; mt++) {
    #pragma unroll
    for (int r = 0; r < 4; r++) {
      int row = ro + 16 * mt + 4 * g + r;
      out[(size_t)row * Cc + o] = x[(size_t)row * Cc + o] + acc[mt][r] + bfo;
    }
  }
}

// ---------------------------------------------------------------------------
extern "C" void kernel_launch(void* const* d_in, const int* in_sizes, int n_in,
                              void* d_out, int out_size, void* d_ws, size_t ws_size,
                              hipStream_t stream) {
  (void)in_sizes; (void)n_in; (void)out_size; (void)ws_size;
  const float* x     = (const float*)d_in[0];
  const float* gam   = (const float*)d_in[1];
  const float* bet   = (const float*)d_in[2];
  const float* Wqkv  = (const float*)d_in[3];
  const float* Wgate = (const float*)d_in[4];
  const float* bgate = (const float*)d_in[5];
  const float* Wf    = (const float*)d_in[6];
  const float* bf    = (const float*)d_in[7];
  float* out = (float*)d_out;
  float* ws  = (float*)d_ws;

  float* normed = ws + OFF_NORMED;
  float* gatep  = ws + OFF_GATE;
  float* mm     = ws + OFF_MM;
  u16*   qhi    = (u16*)(ws + OFF_QHI);
  u16*   qlo    = (u16*)(ws + OFF_QLO);
  u16*   whi    = (u16*)(ws + OFF_WHI);
  u16*   wlo    = (u16*)(ws + OFF_WLO);
  u16*   aohi   = (u16*)(ws + OFF_AOHI);   // aliases normed (dead after proj)
  u16*   aolo   = (u16*)(ws + OFF_AOLO);

  ln_kernel<<<NROWS, 256, 0, stream>>>(x, gam, bet, normed);
  wconv_kernel<<<1280, 256, 0, stream>>>(Wqkv, Wgate, Wf, whi, wlo);
  proj_kernel<<<dim3(16, 64), 256, 0, stream>>>(x, normed, whi, wlo, bgate,
                                                qhi, qlo, gatep);
  stats_kernel<<<dim3(32, 16), 256, 0, stream>>>(qhi, qlo, mm);
  attnout_kernel<<<dim3(32, 16), 256, 0, stream>>>(qhi, qlo, mm, gatep,
                                                   aohi, aolo);
  final_kernel<<<dim3(4, 64), 256, 0, stream>>>(aohi, aolo,
                                                whi + 1024 * Cc, wlo + 1024 * Cc,
                                                bf, x, out);
}